// Round 3
// baseline (345.564 us; speedup 1.0000x reference)
//
#include <hip/hip_runtime.h>
#include <hip/hip_bf16.h>

#define Bc 32
#define Nc 1024
#define Fc 32
#define Dc 64
#define Hc 64
#define NBLK 512

typedef __bf16 bf16;
typedef __bf16 bf16x4 __attribute__((ext_vector_type(4)));
typedef __bf16 bf16x8 __attribute__((ext_vector_type(8)));
typedef float  f32x4  __attribute__((ext_vector_type(4)));

#define MS 72                 // bf16 LDS row stride (144B, 16B-aligned)
#define SMEM_BYTES 39424
// LDS map (single dynamic allocation, phases reuse):
//   init rows : W3sT f32[64][65] @0 (16640) | red f32[256] @16640 | mu4s f32[64] @17664
//   init mu1  : W2s @0 (9216) | xhi @9216 | xlo @14336 | whi @19456 | wlo @24576 | muS @29696..38912
//   rounds    : WHi(=W2s, persists from init) @0 | muHi @9216
//   final     : WHi(Wreg) @0 | muHi @9216 | muLo @18432 | WLo @27648 | rpart f32[128] @36864
//   tail      : mean_s @0 | mp @1024
//
// Fragment-major layouts (16B per lane, coalesced wave loads):
//   Afrag[g][k0][lane][8] : g=n>>4, k0=k>>5, lane=(n&15)+16*((k>>3)&3), j=k&7
//   Xfrag[b][g][k0][lane][8]: g=d>>4, k0=n>>5, lane=(d&15)+16*((n>>3)&3), j=n&7

// ---------------------------------------------------------------------------
// Grid barrier v2: RMW-free polling.
// R2's version polled with atomicAdd(bar,0) (device-scope RMW): 511 pollers
// serialize exclusive ownership of one line at the coherence point -> tens of
// µs per barrier (measured: 265µs kernel, 94% stall). Here: one ACQ_REL
// fetch_add per block on cnt; LAST arriver release-stores flag=phase (written
// once per phase); everyone else spins on RELAXED agent-scope LOADS of flag
// (concurrently serviceable, no ownership transfer). cnt/flag 64B apart.
// Safe: grid=512 == exact co-resident capacity (2 blocks/CU * 256 CU).
// ---------------------------------------------------------------------------
__device__ __forceinline__ void grid_sync(unsigned* cnt, unsigned* flag, unsigned phase) {
    __syncthreads();
    if (threadIdx.x == 0) {
        __threadfence();                       // release: publish prior writes
        const unsigned old =
            __hip_atomic_fetch_add(cnt, 1u, __ATOMIC_ACQ_REL, __HIP_MEMORY_SCOPE_AGENT);
        if (old == (unsigned)NBLK * phase - 1u) {
            __hip_atomic_store(flag, phase, __ATOMIC_RELEASE, __HIP_MEMORY_SCOPE_AGENT);
        } else {
            int guard = 0;
            while (__hip_atomic_load(flag, __ATOMIC_RELAXED, __HIP_MEMORY_SCOPE_AGENT) < phase) {
                __builtin_amdgcn_s_sleep(16);
                if (++guard > (1 << 20)) break;  // fail visibly, never hang
            }
        }
        __threadfence();                       // acquire: invalidate stale caches
    }
    __syncthreads();
}

// ---------------------------------------------------------------------------
// Round body (shared by all 3 rounds). Non-final: WHi (= bf16 W2) persists in
// LDS @0 from the init phase -- no restage. Final: stages Wreg hi/lo.
// ---------------------------------------------------------------------------
template <bool FINAL>
__device__ __forceinline__ void round_body(
    char* smem, int id,
    const bf16* __restrict__ Afrag, const bf16* __restrict__ Xfr_in,
    const float* __restrict__ mu_1, const float* __restrict__ C3,
    bf16* __restrict__ Xfr_out,
    const float* __restrict__ Wreg, const float* __restrict__ c2base,
    const float* __restrict__ Wq, const float* __restrict__ bq,
    float* __restrict__ musum, float* __restrict__ out) {
    const int t = threadIdx.x;
    const int b  = ((id & 7) << 2) | ((id >> 3) & 3);
    const int nb = id >> 5;
    const int n0 = nb * 64;
    const int l = t & 63, wv = t >> 6, lm = l & 15, q = l >> 4;
    const int rh = wv & 1, ch = wv >> 1;
    bf16* WHi  = (bf16*)smem;                 // persists from init (W2) unless FINAL
    bf16* muHi = (bf16*)(smem + 9216);
    bf16* muLo = (bf16*)(smem + 18432);       // FINAL only
    bf16* WLo  = (bf16*)(smem + 27648);       // FINAL only
    float* rpart = (float*)(smem + 36864);    // FINAL [2][64]

    if (FINAL) {
#pragma unroll
        for (int i = 0; i < 4; ++i) {
            int g = i * 1024 + t * 4, h = g >> 6, d = g & 63;
            const float4 w4 = *(const float4*)&Wreg[h * 128 + d];
            bf16x4 ohi, olo;
            ohi[0] = (bf16)w4.x; olo[0] = (bf16)(w4.x - (float)ohi[0]);
            ohi[1] = (bf16)w4.y; olo[1] = (bf16)(w4.y - (float)ohi[1]);
            ohi[2] = (bf16)w4.z; olo[2] = (bf16)(w4.z - (float)ohi[2]);
            ohi[3] = (bf16)w4.w; olo[3] = (bf16)(w4.w - (float)ohi[3]);
            *(bf16x4*)&WHi[h * MS + d] = ohi;
            *(bf16x4*)&WLo[h * MS + d] = olo;
        }
    }

    // ---- K-loop: coalesced fragment streaming, no barriers ----
    f32x4 acc[2][2];
#pragma unroll
    for (int rt = 0; rt < 2; ++rt)
#pragma unroll
        for (int ct = 0; ct < 2; ++ct)
#pragma unroll
            for (int r = 0; r < 4; ++r) acc[rt][ct][r] = 0.f;

    const int gA = nb * 4 + rh * 2;
    const bf16* pa0 = Afrag + (size_t)(gA + 0) * 32 * 512 + l * 8;
    const bf16* pa1 = Afrag + (size_t)(gA + 1) * 32 * 512 + l * 8;
    const bf16* px0 = Xfr_in + (size_t)b * 65536 + (size_t)(ch * 2 + 0) * 32 * 512 + l * 8;
    const bf16* px1 = Xfr_in + (size_t)b * 65536 + (size_t)(ch * 2 + 1) * 32 * 512 + l * 8;
#pragma unroll 4
    for (int k0 = 0; k0 < 32; ++k0) {
        const int o = k0 * 512;
        bf16x8 a0 = *(const bf16x8*)&pa0[o];
        bf16x8 a1 = *(const bf16x8*)&pa1[o];
        bf16x8 x0 = *(const bf16x8*)&px0[o];
        bf16x8 x1 = *(const bf16x8*)&px1[o];
        acc[0][0] = __builtin_amdgcn_mfma_f32_16x16x32_bf16(a0, x0, acc[0][0], 0, 0, 0);
        acc[0][1] = __builtin_amdgcn_mfma_f32_16x16x32_bf16(a0, x1, acc[0][1], 0, 0, 0);
        acc[1][0] = __builtin_amdgcn_mfma_f32_16x16x32_bf16(a1, x0, acc[1][0], 0, 0, 0);
        acc[1][1] = __builtin_amdgcn_mfma_f32_16x16x32_bf16(a1, x1, acc[1][1], 0, 0, 0);
    }

    // ---- epilogue: mu = relu(mu_1 + P + C3) ----
    float vals[2][2][4];
#pragma unroll
    for (int rt = 0; rt < 2; ++rt)
#pragma unroll
        for (int ct = 0; ct < 2; ++ct) {
            const int col = ch * 32 + ct * 16 + lm;
#pragma unroll
            for (int r = 0; r < 4; ++r) {
                const int n = n0 + rh * 32 + rt * 16 + q * 4 + r;
                float v = mu_1[((size_t)b * Nc + n) * Dc + col] + acc[rt][ct][r]
                        + C3[n * 64 + col];
                vals[rt][ct][r] = fmaxf(v, 0.f);
            }
        }

#pragma unroll
    for (int rt = 0; rt < 2; ++rt)
#pragma unroll
        for (int ct = 0; ct < 2; ++ct) {
            const int col = ch * 32 + ct * 16 + lm;
#pragma unroll
            for (int r = 0; r < 4; ++r) {
                const int row = rh * 32 + rt * 16 + q * 4 + r;
                const float v = vals[rt][ct][r];
                const bf16 hi = (bf16)v;
                muHi[row * MS + col] = hi;
                if (FINAL) muLo[row * MS + col] = (bf16)(v - (float)hi);
            }
        }
    if (FINAL) {
#pragma unroll
        for (int ct = 0; ct < 2; ++ct) {
            float s = 0.f;
#pragma unroll
            for (int rt = 0; rt < 2; ++rt)
#pragma unroll
                for (int r = 0; r < 4; ++r) s += vals[rt][ct][r];
            s += __shfl_xor(s, 16);
            s += __shfl_xor(s, 32);
            if (q == 0) atomicAdd(&musum[b * 64 + ch * 32 + ct * 16 + lm], s);
        }
    }
    __syncthreads();

    f32x4 xacc[2][2];
#pragma unroll
    for (int rt = 0; rt < 2; ++rt)
#pragma unroll
        for (int ct = 0; ct < 2; ++ct)
#pragma unroll
            for (int r = 0; r < 4; ++r) xacc[rt][ct][r] = 0.f;

    if (!FINAL) {
#pragma unroll
        for (int s = 0; s < 2; ++s) {
            bf16x8 aM[2], bW[2];
#pragma unroll
            for (int rt = 0; rt < 2; ++rt)
                aM[rt] = *(const bf16x8*)&muHi[(rh * 32 + rt * 16 + lm) * MS + s * 32 + q * 8];
#pragma unroll
            for (int ct = 0; ct < 2; ++ct)
                bW[ct] = *(const bf16x8*)&WHi[(ch * 32 + ct * 16 + lm) * MS + s * 32 + q * 8];
#pragma unroll
            for (int rt = 0; rt < 2; ++rt)
#pragma unroll
                for (int ct = 0; ct < 2; ++ct)
                    xacc[rt][ct] = __builtin_amdgcn_mfma_f32_16x16x32_bf16(aM[rt], bW[ct],
                                                                           xacc[rt][ct], 0, 0, 0);
        }
        // store Xfrag_out: g=ch*2+ct, k0=nb*2+rh, q_c=rt*2+(q>>1), j0=(q&1)*4
        const int k0 = nb * 2 + rh;
        const int q_c0 = (q >> 1), j0 = (q & 1) * 4;
#pragma unroll
        for (int rt = 0; rt < 2; ++rt)
#pragma unroll
            for (int ct = 0; ct < 2; ++ct) {
                bf16x4 p;
#pragma unroll
                for (int r = 0; r < 4; ++r) p[r] = (bf16)xacc[rt][ct][r];
                *(bf16x4*)&Xfr_out[(size_t)b * 65536
                    + (size_t)(((ch * 2 + ct) * 32 + k0) * 64 + lm + 16 * (rt * 2 + q_c0)) * 8
                    + j0] = p;
            }
    } else {
        // head: P2 = muHi@WHi + muLo@WHi + muHi@WLo (split precision)
#pragma unroll
        for (int s = 0; s < 2; ++s) {
            bf16x8 aH[2], aL[2], bH[2], bL[2];
#pragma unroll
            for (int rt = 0; rt < 2; ++rt) {
                const int ao = (rh * 32 + rt * 16 + lm) * MS + s * 32 + q * 8;
                aH[rt] = *(const bf16x8*)&muHi[ao];
                aL[rt] = *(const bf16x8*)&muLo[ao];
            }
#pragma unroll
            for (int ct = 0; ct < 2; ++ct) {
                const int bo = (ch * 32 + ct * 16 + lm) * MS + s * 32 + q * 8;
                bH[ct] = *(const bf16x8*)&WHi[bo];
                bL[ct] = *(const bf16x8*)&WLo[bo];
            }
#pragma unroll
            for (int rt = 0; rt < 2; ++rt)
#pragma unroll
                for (int ct = 0; ct < 2; ++ct) {
                    xacc[rt][ct] = __builtin_amdgcn_mfma_f32_16x16x32_bf16(aH[rt], bH[ct],
                                                                           xacc[rt][ct], 0, 0, 0);
                    xacc[rt][ct] = __builtin_amdgcn_mfma_f32_16x16x32_bf16(aL[rt], bH[ct],
                                                                           xacc[rt][ct], 0, 0, 0);
                    xacc[rt][ct] = __builtin_amdgcn_mfma_f32_16x16x32_bf16(aH[rt], bL[ct],
                                                                           xacc[rt][ct], 0, 0, 0);
                }
        }
        const float bq0 = bq[0];
        float rowsum[2][4] = {{0.f, 0.f, 0.f, 0.f}, {0.f, 0.f, 0.f, 0.f}};
#pragma unroll
        for (int ct = 0; ct < 2; ++ct) {
            const int h = ch * 32 + ct * 16 + lm;
            const float c2 = c2base[b * 64 + h];
            const float wqh = Wq[h];
#pragma unroll
            for (int rt = 0; rt < 2; ++rt)
#pragma unroll
                for (int r = 0; r < 4; ++r)
                    rowsum[rt][r] += fmaxf(xacc[rt][ct][r] + c2, 0.f) * wqh;
        }
#pragma unroll
        for (int rt = 0; rt < 2; ++rt)
#pragma unroll
            for (int r = 0; r < 4; ++r) {
                float v = rowsum[rt][r];
                v += __shfl_xor(v, 1);
                v += __shfl_xor(v, 2);
                v += __shfl_xor(v, 4);
                v += __shfl_xor(v, 8);
                if (lm == 0) rpart[ch * 64 + rh * 32 + rt * 16 + q * 4 + r] = v;
            }
        __syncthreads();
        if (t < 64)
            out[(size_t)b * (Nc + 1) + n0 + t] = rpart[t] + rpart[64 + t] + bq0;
    }
}

// ---------------------------------------------------------------------------
// Fused persistent kernel: init -> r0 -> r1 -> final -> tail, with device
// grid barriers (flag-broadcast, RMW-free polling).
// ---------------------------------------------------------------------------
__global__ __launch_bounds__(256, 2) void k_fused(
    const float* __restrict__ adj, const float* __restrict__ W4,
    const float* __restrict__ b4, const float* __restrict__ W3,
    const float* __restrict__ b3, const float* __restrict__ b2,
    const float* __restrict__ W2, const float* __restrict__ option,
    const float* __restrict__ Wq2, const float* __restrict__ bq2,
    const float* __restrict__ Wreg, const float* __restrict__ breg,
    const float* __restrict__ xv, const float* __restrict__ mu1w,
    const float* __restrict__ Wq1, const float* __restrict__ bq1,
    const float* __restrict__ Wq, const float* __restrict__ bq,
    bf16* __restrict__ Afrag, float* __restrict__ C3,
    float* __restrict__ c2base, float* __restrict__ musum,
    float* __restrict__ mu_1, bf16* __restrict__ Xf0, bf16* __restrict__ Xf1,
    float* __restrict__ out, unsigned* __restrict__ bar) {
    const int id = blockIdx.x, t = threadIdx.x;
    unsigned* cnt  = bar;         // arrival counter
    unsigned* flag = bar + 16;    // phase flag, separate cache line
    extern __shared__ char smem[];

    // ================= INIT =================
    // small per-b tasks on low block ids (no LDS)
    if (id < 8) {
        musum[id * 256 + t] = 0.f;
    } else if (id < 16) {
        const int i = (id - 8) * 256 + t, b = i >> 6, h = i & 63;
        const float opt = option[b];
        float a = breg[h];
#pragma unroll
        for (int j = 0; j < 64; ++j)
            a = fmaf(fmaf(opt, Wq2[j], bq2[j]), Wreg[h * 128 + 64 + j], a);
        c2base[i] = a;
    }
    // rows 2id, 2id+1: binarize Afrag + mu4 + C3 (W3 via padded-transpose LDS)
    {
        float* W3sT = (float*)smem;             // [64][65]
        float* red  = (float*)(smem + 16640);   // [256]
        float* mu4s = (float*)(smem + 17664);   // [64]
        for (int i = t; i < 4096; i += 256) {
            const int r = i >> 6, c = i & 63;
            W3sT[c * 65 + r] = W3[i];           // W3sT[e][d] = W3[d][e]
        }
        for (int rr = 0; rr < 2; ++rr) {
            const int n = id * 2 + rr;
            const float* arow = adj + (size_t)n * Nc;
            {   // binarize row n into Afrag
                const int m0 = t * 4;
                const float4 a = *(const float4*)&arow[m0];
                bf16x4 o;
                o[0] = (bf16)((a.x > 0.f) ? 1.f : 0.f);
                o[1] = (bf16)((a.y > 0.f) ? 1.f : 0.f);
                o[2] = (bf16)((a.z > 0.f) ? 1.f : 0.f);
                o[3] = (bf16)((a.w > 0.f) ? 1.f : 0.f);
                const int g = n >> 4, lm = n & 15;
                const int k0 = m0 >> 5, qq = (m0 & 31) >> 3, j = m0 & 7;
                *(bf16x4*)&Afrag[(size_t)((g * 32 + k0) * 64 + lm + 16 * qq) * 8 + j] = o;
            }
            const int e = t & 63, g = t >> 6;
            const float w4e = W4[e], b4e = b4[e];
            float acc = 0.f;
            const float4* arow4 = (const float4*)(arow + g * 256);
#pragma unroll 8
            for (int j = 0; j < 64; ++j) {
                const float4 av = arow4[j];
                acc += fmaxf(fmaf(av.x, w4e, b4e), 0.f);
                acc += fmaxf(fmaf(av.y, w4e, b4e), 0.f);
                acc += fmaxf(fmaf(av.z, w4e, b4e), 0.f);
                acc += fmaxf(fmaf(av.w, w4e, b4e), 0.f);
            }
            red[t] = acc;
            __syncthreads();
            if (g == 0) mu4s[e] = red[e] + red[64 + e] + red[128 + e] + red[192 + e];
            __syncthreads();
            if (t < 64) {
                float a = b3[t] + b2[t];
#pragma unroll
                for (int ee = 0; ee < 64; ++ee) a = fmaf(mu4s[ee], W3sT[ee * 65 + t], a);
                C3[n * 64 + t] = a;
            }
            __syncthreads();
        }
    }
    // mu1-part: one (b, nb) tile per block; fills W2s (persists as WHi @0)
    {
        const int nb = id & 15, b = id >> 4;
        const int n0 = nb * 64;
        const int l = t & 63, wv = t >> 6, lm = l & 15, q = l >> 4;
        bf16* W2s = (bf16*)smem;              // [64][72] = 9216  (persists!)
        bf16* xhi = (bf16*)(smem + 9216);     // [64][40] = 5120
        bf16* xlo = (bf16*)(smem + 14336);
        bf16* whi = (bf16*)(smem + 19456);
        bf16* wlo = (bf16*)(smem + 24576);
        bf16* muS = (bf16*)(smem + 29696);    // [64][72], end 38912
        {
            const int row = t >> 2, f0 = (t & 3) * 8;
            const float* src = &xv[((size_t)b * Nc + n0 + row) * Fc + f0];
            const float4 v0 = *(const float4*)src;
            const float4 v1 = *(const float4*)(src + 4);
            bf16x8 hi, lo;
            float vv[8] = {v0.x, v0.y, v0.z, v0.w, v1.x, v1.y, v1.z, v1.w};
#pragma unroll
            for (int j = 0; j < 8; ++j) { hi[j] = (bf16)vv[j]; lo[j] = (bf16)(vv[j] - (float)hi[j]); }
            *(bf16x8*)&xhi[row * 40 + f0] = hi;
            *(bf16x8*)&xlo[row * 40 + f0] = lo;
        }
        {
            const int d = t >> 2, f0 = (t & 3) * 8;
#pragma unroll
            for (int j = 0; j < 8; ++j) {
                const float v = mu1w[(f0 + j) * Dc + d];
                const bf16 hi = (bf16)v;
                whi[d * 40 + f0 + j] = hi;
                wlo[d * 40 + f0 + j] = (bf16)(v - (float)hi);
            }
        }
        {   // W2s[d][e] from fp32 W2
            const int row = t >> 2, c0 = (t & 3) * 16;
            const float4 v0 = *(const float4*)&W2[row * 64 + c0];
            const float4 v1 = *(const float4*)&W2[row * 64 + c0 + 4];
            const float4 v2 = *(const float4*)&W2[row * 64 + c0 + 8];
            const float4 v3 = *(const float4*)&W2[row * 64 + c0 + 12];
            bf16x8 p0, p1;
            p0[0]=(bf16)v0.x; p0[1]=(bf16)v0.y; p0[2]=(bf16)v0.z; p0[3]=(bf16)v0.w;
            p0[4]=(bf16)v1.x; p0[5]=(bf16)v1.y; p0[6]=(bf16)v1.z; p0[7]=(bf16)v1.w;
            p1[0]=(bf16)v2.x; p1[1]=(bf16)v2.y; p1[2]=(bf16)v2.z; p1[3]=(bf16)v2.w;
            p1[4]=(bf16)v3.x; p1[5]=(bf16)v3.y; p1[6]=(bf16)v3.z; p1[7]=(bf16)v3.w;
            *(bf16x8*)&W2s[row * MS + c0] = p0;
            *(bf16x8*)&W2s[row * MS + c0 + 8] = p1;
        }
        __syncthreads();
        f32x4 acc[4];
#pragma unroll
        for (int ct = 0; ct < 4; ++ct)
#pragma unroll
            for (int r = 0; r < 4; ++r) acc[ct][r] = 0.f;
        {
            const bf16x8 aHi = *(const bf16x8*)&xhi[(wv * 16 + lm) * 40 + q * 8];
            const bf16x8 aLo = *(const bf16x8*)&xlo[(wv * 16 + lm) * 40 + q * 8];
#pragma unroll
            for (int ct = 0; ct < 4; ++ct) {
                const bf16x8 bHi = *(const bf16x8*)&whi[(ct * 16 + lm) * 40 + q * 8];
                const bf16x8 bLo = *(const bf16x8*)&wlo[(ct * 16 + lm) * 40 + q * 8];
                acc[ct] = __builtin_amdgcn_mfma_f32_16x16x32_bf16(aHi, bHi, acc[ct], 0, 0, 0);
                acc[ct] = __builtin_amdgcn_mfma_f32_16x16x32_bf16(aLo, bHi, acc[ct], 0, 0, 0);
                acc[ct] = __builtin_amdgcn_mfma_f32_16x16x32_bf16(aHi, bLo, acc[ct], 0, 0, 0);
            }
        }
#pragma unroll
        for (int ct = 0; ct < 4; ++ct) {
            const int col = ct * 16 + lm;
#pragma unroll
            for (int r = 0; r < 4; ++r) {
                const int row = wv * 16 + q * 4 + r;
                const float v = fmaxf(acc[ct][r], 0.f);
                mu_1[((size_t)b * Nc + n0 + row) * Dc + col] = v;
                muS[row * MS + col] = (bf16)v;
            }
        }
        __syncthreads();
        f32x4 xacc[4];
#pragma unroll
        for (int ct = 0; ct < 4; ++ct)
#pragma unroll
            for (int r = 0; r < 4; ++r) xacc[ct][r] = 0.f;
#pragma unroll
        for (int s = 0; s < 2; ++s) {
            bf16x8 a = *(const bf16x8*)&muS[(wv * 16 + lm) * MS + s * 32 + q * 8];
#pragma unroll
            for (int ct = 0; ct < 4; ++ct) {
                bf16x8 bv = *(const bf16x8*)&W2s[(ct * 16 + lm) * MS + s * 32 + q * 8];
                xacc[ct] = __builtin_amdgcn_mfma_f32_16x16x32_bf16(a, bv, xacc[ct], 0, 0, 0);
            }
        }
        const int k0 = nb * 2 + (wv >> 1);
        const int q_c = (wv & 1) * 2 + (q >> 1);
        const int j0 = (q & 1) * 4;
#pragma unroll
        for (int ct = 0; ct < 4; ++ct) {
            bf16x4 p;
#pragma unroll
            for (int r = 0; r < 4; ++r) p[r] = (bf16)xacc[ct][r];
            *(bf16x4*)&Xf0[(size_t)b * 65536
                           + (size_t)((ct * 32 + k0) * 64 + lm + 16 * q_c) * 8 + j0] = p;
        }
    }
    grid_sync(cnt, flag, 1);

    // ================= ROUNDS =================
    round_body<false>(smem, id, Afrag, Xf0, mu_1, C3, Xf1,
                      nullptr, nullptr, nullptr, nullptr, nullptr, nullptr);
    grid_sync(cnt, flag, 2);
    round_body<false>(smem, id, Afrag, Xf1, mu_1, C3, Xf0,
                      nullptr, nullptr, nullptr, nullptr, nullptr, nullptr);
    grid_sync(cnt, flag, 3);
    round_body<true>(smem, id, Afrag, Xf0, mu_1, C3, nullptr,
                     Wreg, c2base, Wq, bq, musum, out);
    grid_sync(cnt, flag, 4);

    // ================= TAIL (mean row) =================
    if (id < 32) {
        const int b = id;
        float* mean_s = (float*)smem;
        float* mp     = (float*)(smem + 1024);
        if (t < 64) mean_s[t] = musum[b * 64 + t] * (1.f / Nc);
        __syncthreads();
        if (t < 64) {
            float a = bq1[t];
#pragma unroll
            for (int e = 0; e < 64; ++e) a = fmaf(mean_s[e], Wq1[t * 64 + e], a);
            mp[t] = fmaxf(a, 0.f);
        }
        __syncthreads();
        if (t < 64) {
            float h = c2base[b * 64 + t];
#pragma unroll
            for (int d = 0; d < 64; ++d) h = fmaf(mp[d], Wreg[t * 128 + d], h);
            float v = fmaxf(h, 0.f) * Wq[t];
#pragma unroll
            for (int off = 32; off; off >>= 1) v += __shfl_down(v, off);
            if (t == 0) out[(size_t)b * (Nc + 1) + Nc] = v + bq[0];
        }
    }
}

// ---------------------------------------------------------------------------
extern "C" void kernel_launch(void* const* d_in, const int* in_sizes, int n_in,
                              void* d_out, int out_size, void* d_ws, size_t ws_size,
                              hipStream_t stream) {
    const float* xv     = (const float*)d_in[0];
    const float* option = (const float*)d_in[1];
    const float* adj    = (const float*)d_in[2];
    const float* mu1w   = (const float*)d_in[3];
    const float* W2     = (const float*)d_in[4];
    const float* b2     = (const float*)d_in[5];
    const float* W3     = (const float*)d_in[6];
    const float* b3     = (const float*)d_in[7];
    const float* W4     = (const float*)d_in[8];
    const float* b4     = (const float*)d_in[9];
    const float* Wq1    = (const float*)d_in[10];
    const float* bq1    = (const float*)d_in[11];
    const float* Wq2    = (const float*)d_in[12];
    const float* bq2    = (const float*)d_in[13];
    const float* Wreg   = (const float*)d_in[14];
    const float* breg   = (const float*)d_in[15];
    const float* Wq     = (const float*)d_in[16];
    const float* bq     = (const float*)d_in[17];
    float* out = (float*)d_out;

    float* ws = (float*)d_ws;
    const size_t MU = (size_t)Bc * Nc * Dc;          // 2,097,152
    float* mu_1     = ws;
    float* C3       = ws + MU;                       // 65536
    float* c2base   = C3 + 65536;                    // 2048
    float* musum    = c2base + 2048;                 // 2048
    unsigned* bar   = (unsigned*)(musum + 2048);     // 32 uints (cnt@0, flag@16)
    bf16*  Afrag    = (bf16*)(bar + 32);             // 1M bf16
    bf16*  Xf0      = Afrag + (size_t)Nc * Nc;       // B*64K bf16
    bf16*  Xf1      = Xf0 + MU;

    hipMemsetAsync(bar, 0, 128, stream);
    k_fused<<<NBLK, 256, SMEM_BYTES, stream>>>(
        adj, W4, b4, W3, b3, b2, W2, option, Wq2, bq2, Wreg, breg, xv, mu1w,
        Wq1, bq1, Wq, bq,
        Afrag, C3, c2base, musum, mu_1, Xf0, Xf1, out, bar);
}

// Round 4
// 173.328 us; speedup vs baseline: 1.9937x; 1.9937x over previous
//
#include <hip/hip_runtime.h>
#include <hip/hip_bf16.h>

#define Bc 32
#define Nc 1024
#define Fc 32
#define Dc 64
#define Hc 64
#define NBLK 512

typedef __bf16 bf16;
typedef __bf16 bf16x4 __attribute__((ext_vector_type(4)));
typedef __bf16 bf16x8 __attribute__((ext_vector_type(8)));
typedef float  f32x4  __attribute__((ext_vector_type(4)));

#define MS 72                 // bf16 LDS row stride (144B, 16B-aligned)
#define LDS_RND 37376         // WHi | muHi | muLo | WLo | rpart (final layout, superset)

// Fragment-major layouts (16B per lane, coalesced wave loads):
//   Afrag[g][k0][lane][8] : g=n>>4, k0=k>>5, lane=(n&15)+16*((k>>3)&3), j=k&7
//   Xfrag[b][g][k0][lane][8]: g=d>>4, k0=n>>5, lane=(d&15)+16*((n>>3)&3), j=n&7
//
// FUSION CONTRACT (fence-free):
//  * k_init is a separate kernel: its outputs (Afrag, Xf0, mu_1, C3, W2bf,
//    c2base, musum=0, bar=0) are published by the end-of-kernel L2 writeback;
//    k_rounds3's launch acquire-invalidates stale lines. No fences needed.
//  * Inside k_rounds3, the ONLY cross-block intra-kernel data are X-frags and
//    musum. These move through the MALL (device coherence point) via
//    device-scope RELAXED atomics (sc0 sc1) -> correct regardless of
//    block->XCD mapping, and requires ZERO cache-maintenance instructions.
//    (R2/R3 post-mortem: __threadfence() x2 per block per barrier = 4096
//    whole-L2 writeback/invalidates = ~250us stall, 94% idle.)
//  * A/mu_1/C3/W2bf are written only before the rounds kernel -> plain
//    cached loads are legal in all rounds (no stale copies can exist).
//  * Barrier: s_waitcnt vmcnt(0) by ALL threads (sc1 write-acks reach MALL),
//    one relaxed fetch_add, last arriver relaxed-stores flag, rest spin on
//    relaxed loads. Guard-loop breaks visibly if co-residency ever fails.

// ---------------------------------------------------------------------------
template <bool BY>
__device__ __forceinline__ bf16x8 ld_x8(const bf16* p) {
    if (BY) {
        union { unsigned long long u[2]; bf16x8 v; } r;
        r.u[0] = __hip_atomic_load((const unsigned long long*)p,
                                   __ATOMIC_RELAXED, __HIP_MEMORY_SCOPE_AGENT);
        r.u[1] = __hip_atomic_load((const unsigned long long*)(p + 4),
                                   __ATOMIC_RELAXED, __HIP_MEMORY_SCOPE_AGENT);
        return r.v;
    } else {
        return *(const bf16x8*)p;
    }
}

__device__ __forceinline__ void st_x4(bf16* p, bf16x4 v) {
    union { bf16x4 v; unsigned long long u; } r;
    r.v = v;
    __hip_atomic_store((unsigned long long*)p, r.u,
                       __ATOMIC_RELAXED, __HIP_MEMORY_SCOPE_AGENT);
}

__device__ __forceinline__ void sync_lite(unsigned* cnt, unsigned* flag, unsigned phase) {
    asm volatile("s_waitcnt vmcnt(0)" ::: "memory");  // all waves: sc1 writes ACKed at MALL
    __syncthreads();
    if (threadIdx.x == 0) {
        const unsigned old =
            __hip_atomic_fetch_add(cnt, 1u, __ATOMIC_RELAXED, __HIP_MEMORY_SCOPE_AGENT);
        if (old == (unsigned)NBLK * phase - 1u) {
            __hip_atomic_store(flag, phase, __ATOMIC_RELAXED, __HIP_MEMORY_SCOPE_AGENT);
        } else {
            int guard = 0;
            while (__hip_atomic_load(flag, __ATOMIC_RELAXED, __HIP_MEMORY_SCOPE_AGENT) < phase) {
                __builtin_amdgcn_s_sleep(8);
                if (++guard > (1 << 21)) break;       // fail visibly, never hang
            }
        }
    }
    __syncthreads();
}

// ---------------------------------------------------------------------------
// k_init: identical to the verified 152us split version, plus bar zeroing.
// blocks 0..1023 (n=id): Afrag row n (binarized) + C3[n][:]
// block 1024: W2bf, musum zero, c2base, bar zero
// blocks 1025..1536: mu1-part: mu_1 = relu(xv@mu1); Xfrag0 = mu_1@W2^T
// ---------------------------------------------------------------------------
__global__ void k_init(const float* __restrict__ adj, const float* __restrict__ W4,
                       const float* __restrict__ b4, const float* __restrict__ W3,
                       const float* __restrict__ b3, const float* __restrict__ b2,
                       const float* __restrict__ W2, const float* __restrict__ option,
                       const float* __restrict__ Wq2, const float* __restrict__ bq2,
                       const float* __restrict__ Wreg, const float* __restrict__ breg,
                       const float* __restrict__ xv, const float* __restrict__ mu1w,
                       bf16* __restrict__ Afrag, float* __restrict__ C3,
                       bf16* __restrict__ W2bf, float* __restrict__ c2base,
                       float* __restrict__ musum,
                       float* __restrict__ mu_1, bf16* __restrict__ Xfrag0,
                       unsigned* __restrict__ bar) {
    const int id = blockIdx.x, t = threadIdx.x;
    __shared__ char smem[39424];
    if (id < 1024) {
        const int n = id;
        float* red   = (float*)smem;
        float* mu4_s = red + 256;
        const float* arow = adj + (size_t)n * Nc;
        {   // binarize row n into Afrag
            const int m0 = t * 4;
            const float4 a = *(const float4*)&arow[m0];
            bf16x4 o;
            o[0] = (bf16)((a.x > 0.f) ? 1.f : 0.f);
            o[1] = (bf16)((a.y > 0.f) ? 1.f : 0.f);
            o[2] = (bf16)((a.z > 0.f) ? 1.f : 0.f);
            o[3] = (bf16)((a.w > 0.f) ? 1.f : 0.f);
            const int g = n >> 4, lm = n & 15;
            const int k0 = m0 >> 5, q = (m0 & 31) >> 3, j = m0 & 7;
            *(bf16x4*)&Afrag[(size_t)((g * 32 + k0) * 64 + lm + 16 * q) * 8 + j] = o;
        }
        const int e = t & 63, g = t >> 6;
        const float w4e = W4[e], b4e = b4[e];
        float acc = 0.f;
        const float4* arow4 = (const float4*)(arow + g * 256);
#pragma unroll 8
        for (int j = 0; j < 64; ++j) {
            const float4 av = arow4[j];
            acc += fmaxf(fmaf(av.x, w4e, b4e), 0.f);
            acc += fmaxf(fmaf(av.y, w4e, b4e), 0.f);
            acc += fmaxf(fmaf(av.z, w4e, b4e), 0.f);
            acc += fmaxf(fmaf(av.w, w4e, b4e), 0.f);
        }
        red[t] = acc;
        __syncthreads();
        if (g == 0) mu4_s[e] = red[e] + red[64 + e] + red[128 + e] + red[192 + e];
        __syncthreads();
        if (t < 64) {
            const int d = t;
            float a = b3[d] + b2[d];
#pragma unroll
            for (int ee = 0; ee < 64; ++ee) a = fmaf(mu4_s[ee], W3[d * 64 + ee], a);
            C3[n * 64 + d] = a;
        }
    } else if (id == 1024) {
        for (int j = t * 16; j < t * 16 + 16; ++j) W2bf[j] = (bf16)W2[j];
        for (int i = t; i < 2048; i += 256) musum[i] = 0.f;
        if (t < 64) bar[t] = 0u;
        for (int i = t; i < 2048; i += 256) {
            const int b = i >> 6, h = i & 63;
            const float opt = option[b];
            float a = breg[h];
#pragma unroll
            for (int j = 0; j < 64; ++j)
                a = fmaf(fmaf(opt, Wq2[j], bq2[j]), Wreg[h * 128 + 64 + j], a);
            c2base[i] = a;
        }
    } else {
        // ---- mu1-part: 64-row tile ----
        const int idx = id - 1025, nb = idx & 15, b = idx >> 4;
        const int n0 = nb * 64;
        const int l = t & 63, wv = t >> 6, lm = l & 15, q = l >> 4;
        bf16* W2s = (bf16*)smem;              // [64][72] = 9216
        bf16* xhi = (bf16*)(smem + 9216);     // [64][40] = 5120
        bf16* xlo = (bf16*)(smem + 14336);
        bf16* whi = (bf16*)(smem + 19456);
        bf16* wlo = (bf16*)(smem + 24576);    // end 29696
        bf16* muS = (bf16*)(smem + 29696);    // [64][72] = 9216, end 38912
        {
            const int row = t >> 2, f0 = (t & 3) * 8;
            const float* src = &xv[((size_t)b * Nc + n0 + row) * Fc + f0];
            const float4 v0 = *(const float4*)src;
            const float4 v1 = *(const float4*)(src + 4);
            bf16x8 hi, lo;
            float vv[8] = {v0.x, v0.y, v0.z, v0.w, v1.x, v1.y, v1.z, v1.w};
#pragma unroll
            for (int j = 0; j < 8; ++j) { hi[j] = (bf16)vv[j]; lo[j] = (bf16)(vv[j] - (float)hi[j]); }
            *(bf16x8*)&xhi[row * 40 + f0] = hi;
            *(bf16x8*)&xlo[row * 40 + f0] = lo;
        }
        {
            const int d = t >> 2, f0 = (t & 3) * 8;
#pragma unroll
            for (int j = 0; j < 8; ++j) {
                const float v = mu1w[(f0 + j) * Dc + d];
                const bf16 hi = (bf16)v;
                whi[d * 40 + f0 + j] = hi;
                wlo[d * 40 + f0 + j] = (bf16)(v - (float)hi);
            }
        }
        {   // W2s[d][e] from fp32 W2
            const int row = t >> 2, c0 = (t & 3) * 16;
            const float4 v0 = *(const float4*)&W2[row * 64 + c0];
            const float4 v1 = *(const float4*)&W2[row * 64 + c0 + 4];
            const float4 v2 = *(const float4*)&W2[row * 64 + c0 + 8];
            const float4 v3 = *(const float4*)&W2[row * 64 + c0 + 12];
            bf16x8 p0, p1;
            p0[0]=(bf16)v0.x; p0[1]=(bf16)v0.y; p0[2]=(bf16)v0.z; p0[3]=(bf16)v0.w;
            p0[4]=(bf16)v1.x; p0[5]=(bf16)v1.y; p0[6]=(bf16)v1.z; p0[7]=(bf16)v1.w;
            p1[0]=(bf16)v2.x; p1[1]=(bf16)v2.y; p1[2]=(bf16)v2.z; p1[3]=(bf16)v2.w;
            p1[4]=(bf16)v3.x; p1[5]=(bf16)v3.y; p1[6]=(bf16)v3.z; p1[7]=(bf16)v3.w;
            *(bf16x8*)&W2s[row * MS + c0] = p0;
            *(bf16x8*)&W2s[row * MS + c0 + 8] = p1;
        }
        __syncthreads();
        f32x4 acc[4];
#pragma unroll
        for (int ct = 0; ct < 4; ++ct)
#pragma unroll
            for (int r = 0; r < 4; ++r) acc[ct][r] = 0.f;
        {
            const bf16x8 aHi = *(const bf16x8*)&xhi[(wv * 16 + lm) * 40 + q * 8];
            const bf16x8 aLo = *(const bf16x8*)&xlo[(wv * 16 + lm) * 40 + q * 8];
#pragma unroll
            for (int ct = 0; ct < 4; ++ct) {
                const bf16x8 bHi = *(const bf16x8*)&whi[(ct * 16 + lm) * 40 + q * 8];
                const bf16x8 bLo = *(const bf16x8*)&wlo[(ct * 16 + lm) * 40 + q * 8];
                acc[ct] = __builtin_amdgcn_mfma_f32_16x16x32_bf16(aHi, bHi, acc[ct], 0, 0, 0);
                acc[ct] = __builtin_amdgcn_mfma_f32_16x16x32_bf16(aLo, bHi, acc[ct], 0, 0, 0);
                acc[ct] = __builtin_amdgcn_mfma_f32_16x16x32_bf16(aHi, bLo, acc[ct], 0, 0, 0);
            }
        }
#pragma unroll
        for (int ct = 0; ct < 4; ++ct) {
            const int col = ct * 16 + lm;
#pragma unroll
            for (int r = 0; r < 4; ++r) {
                const int row = wv * 16 + q * 4 + r;
                const float v = fmaxf(acc[ct][r], 0.f);
                mu_1[((size_t)b * Nc + n0 + row) * Dc + col] = v;
                muS[row * MS + col] = (bf16)v;
            }
        }
        __syncthreads();
        f32x4 xacc[4];
#pragma unroll
        for (int ct = 0; ct < 4; ++ct)
#pragma unroll
            for (int r = 0; r < 4; ++r) xacc[ct][r] = 0.f;
#pragma unroll
        for (int s = 0; s < 2; ++s) {
            bf16x8 a = *(const bf16x8*)&muS[(wv * 16 + lm) * MS + s * 32 + q * 8];
#pragma unroll
            for (int ct = 0; ct < 4; ++ct) {
                bf16x8 bv = *(const bf16x8*)&W2s[(ct * 16 + lm) * MS + s * 32 + q * 8];
                xacc[ct] = __builtin_amdgcn_mfma_f32_16x16x32_bf16(a, bv, xacc[ct], 0, 0, 0);
            }
        }
        // store Xfrag0: g=ct, k0=nb*2+(wv>>1), q_c=(wv&1)*2+(q>>1), j0=(q&1)*4
        const int k0 = nb * 2 + (wv >> 1);
        const int q_c = (wv & 1) * 2 + (q >> 1);
        const int j0 = (q & 1) * 4;
#pragma unroll
        for (int ct = 0; ct < 4; ++ct) {
            bf16x4 p;
#pragma unroll
            for (int r = 0; r < 4; ++r) p[r] = (bf16)xacc[ct][r];
            *(bf16x4*)&Xfrag0[(size_t)b * 65536
                              + (size_t)((ct * 32 + k0) * 64 + lm + 16 * q_c) * 8 + j0] = p;
        }
    }
}

// ---------------------------------------------------------------------------
// Round body. WHi (bf16 W2) staged ONCE by caller, persists in LDS across
// rounds. X-frags read/written through MALL (sc1) when XBY is set.
// ---------------------------------------------------------------------------
template <bool FINAL, bool XBY>
__device__ __forceinline__ void round_body(
    char* smem, int id,
    const bf16* __restrict__ Afrag, const bf16* __restrict__ Xfr_in,
    const float* __restrict__ mu_1, const float* __restrict__ C3,
    bf16* __restrict__ Xfr_out,
    const float* __restrict__ Wreg, const float* __restrict__ c2base,
    const float* __restrict__ Wq, const float* __restrict__ bq,
    float* __restrict__ musum, float* __restrict__ out) {
    const int t = threadIdx.x;
    const int b  = ((id & 7) << 2) | ((id >> 3) & 3);
    const int nb = id >> 5;
    const int n0 = nb * 64;
    const int l = t & 63, wv = t >> 6, lm = l & 15, q = l >> 4;
    const int rh = wv & 1, ch = wv >> 1;
    bf16* WHi  = (bf16*)smem;                 // persists across non-final rounds
    bf16* muHi = (bf16*)(smem + 9216);
    bf16* muLo = (bf16*)(smem + 18432);       // FINAL only
    bf16* WLo  = (bf16*)(smem + 27648);       // FINAL only
    float* rpart = (float*)(smem + 36864);    // FINAL [2][64]

    if (FINAL) {
#pragma unroll
        for (int i = 0; i < 4; ++i) {
            int g = i * 1024 + t * 4, h = g >> 6, d = g & 63;
            const float4 w4 = *(const float4*)&Wreg[h * 128 + d];
            bf16x4 ohi, olo;
            ohi[0] = (bf16)w4.x; olo[0] = (bf16)(w4.x - (float)ohi[0]);
            ohi[1] = (bf16)w4.y; olo[1] = (bf16)(w4.y - (float)ohi[1]);
            ohi[2] = (bf16)w4.z; olo[2] = (bf16)(w4.z - (float)ohi[2]);
            ohi[3] = (bf16)w4.w; olo[3] = (bf16)(w4.w - (float)ohi[3]);
            *(bf16x4*)&WHi[h * MS + d] = ohi;
            *(bf16x4*)&WLo[h * MS + d] = olo;
        }
    }

    // ---- K-loop: coalesced fragment streaming, no barriers ----
    f32x4 acc[2][2];
#pragma unroll
    for (int rt = 0; rt < 2; ++rt)
#pragma unroll
        for (int ct = 0; ct < 2; ++ct)
#pragma unroll
            for (int r = 0; r < 4; ++r) acc[rt][ct][r] = 0.f;

    const int gA = nb * 4 + rh * 2;
    const bf16* pa0 = Afrag + (size_t)(gA + 0) * 32 * 512 + l * 8;
    const bf16* pa1 = Afrag + (size_t)(gA + 1) * 32 * 512 + l * 8;
    const bf16* px0 = Xfr_in + (size_t)b * 65536 + (size_t)(ch * 2 + 0) * 32 * 512 + l * 8;
    const bf16* px1 = Xfr_in + (size_t)b * 65536 + (size_t)(ch * 2 + 1) * 32 * 512 + l * 8;
#pragma unroll 4
    for (int k0 = 0; k0 < 32; ++k0) {
        const int o = k0 * 512;
        bf16x8 a0 = *(const bf16x8*)&pa0[o];
        bf16x8 a1 = *(const bf16x8*)&pa1[o];
        bf16x8 x0 = ld_x8<XBY>(&px0[o]);
        bf16x8 x1 = ld_x8<XBY>(&px1[o]);
        acc[0][0] = __builtin_amdgcn_mfma_f32_16x16x32_bf16(a0, x0, acc[0][0], 0, 0, 0);
        acc[0][1] = __builtin_amdgcn_mfma_f32_16x16x32_bf16(a0, x1, acc[0][1], 0, 0, 0);
        acc[1][0] = __builtin_amdgcn_mfma_f32_16x16x32_bf16(a1, x0, acc[1][0], 0, 0, 0);
        acc[1][1] = __builtin_amdgcn_mfma_f32_16x16x32_bf16(a1, x1, acc[1][1], 0, 0, 0);
    }

    // ---- epilogue: mu = relu(mu_1 + P + C3) ----
    float vals[2][2][4];
#pragma unroll
    for (int rt = 0; rt < 2; ++rt)
#pragma unroll
        for (int ct = 0; ct < 2; ++ct) {
            const int col = ch * 32 + ct * 16 + lm;
#pragma unroll
            for (int r = 0; r < 4; ++r) {
                const int n = n0 + rh * 32 + rt * 16 + q * 4 + r;
                float v = mu_1[((size_t)b * Nc + n) * Dc + col] + acc[rt][ct][r]
                        + C3[n * 64 + col];
                vals[rt][ct][r] = fmaxf(v, 0.f);
            }
        }

#pragma unroll
    for (int rt = 0; rt < 2; ++rt)
#pragma unroll
        for (int ct = 0; ct < 2; ++ct) {
            const int col = ch * 32 + ct * 16 + lm;
#pragma unroll
            for (int r = 0; r < 4; ++r) {
                const int row = rh * 32 + rt * 16 + q * 4 + r;
                const float v = vals[rt][ct][r];
                const bf16 hi = (bf16)v;
                muHi[row * MS + col] = hi;
                if (FINAL) muLo[row * MS + col] = (bf16)(v - (float)hi);
            }
        }
    if (FINAL) {
#pragma unroll
        for (int ct = 0; ct < 2; ++ct) {
            float s = 0.f;
#pragma unroll
            for (int rt = 0; rt < 2; ++rt)
#pragma unroll
                for (int r = 0; r < 4; ++r) s += vals[rt][ct][r];
            s += __shfl_xor(s, 16);
            s += __shfl_xor(s, 32);
            if (q == 0) atomicAdd(&musum[b * 64 + ch * 32 + ct * 16 + lm], s);
        }
    }
    __syncthreads();

    f32x4 xacc[2][2];
#pragma unroll
    for (int rt = 0; rt < 2; ++rt)
#pragma unroll
        for (int ct = 0; ct < 2; ++ct)
#pragma unroll
            for (int r = 0; r < 4; ++r) xacc[rt][ct][r] = 0.f;

    if (!FINAL) {
#pragma unroll
        for (int s = 0; s < 2; ++s) {
            bf16x8 aM[2], bW[2];
#pragma unroll
            for (int rt = 0; rt < 2; ++rt)
                aM[rt] = *(const bf16x8*)&muHi[(rh * 32 + rt * 16 + lm) * MS + s * 32 + q * 8];
#pragma unroll
            for (int ct = 0; ct < 2; ++ct)
                bW[ct] = *(const bf16x8*)&WHi[(ch * 32 + ct * 16 + lm) * MS + s * 32 + q * 8];
#pragma unroll
            for (int rt = 0; rt < 2; ++rt)
#pragma unroll
                for (int ct = 0; ct < 2; ++ct)
                    xacc[rt][ct] = __builtin_amdgcn_mfma_f32_16x16x32_bf16(aM[rt], bW[ct],
                                                                           xacc[rt][ct], 0, 0, 0);
        }
        // store Xfrag_out via MALL: g=ch*2+ct, k0=nb*2+rh, q_c=rt*2+(q>>1), j0=(q&1)*4
        const int k0 = nb * 2 + rh;
        const int q_c0 = (q >> 1), j0 = (q & 1) * 4;
#pragma unroll
        for (int rt = 0; rt < 2; ++rt)
#pragma unroll
            for (int ct = 0; ct < 2; ++ct) {
                bf16x4 p;
#pragma unroll
                for (int r = 0; r < 4; ++r) p[r] = (bf16)xacc[rt][ct][r];
                st_x4(&Xfr_out[(size_t)b * 65536
                    + (size_t)(((ch * 2 + ct) * 32 + k0) * 64 + lm + 16 * (rt * 2 + q_c0)) * 8
                    + j0], p);
            }
    } else {
        // head: P2 = muHi@WHi + muLo@WHi + muHi@WLo (split precision)
#pragma unroll
        for (int s = 0; s < 2; ++s) {
            bf16x8 aH[2], aL[2], bH[2], bL[2];
#pragma unroll
            for (int rt = 0; rt < 2; ++rt) {
                const int ao = (rh * 32 + rt * 16 + lm) * MS + s * 32 + q * 8;
                aH[rt] = *(const bf16x8*)&muHi[ao];
                aL[rt] = *(const bf16x8*)&muLo[ao];
            }
#pragma unroll
            for (int ct = 0; ct < 2; ++ct) {
                const int bo = (ch * 32 + ct * 16 + lm) * MS + s * 32 + q * 8;
                bH[ct] = *(const bf16x8*)&WHi[bo];
                bL[ct] = *(const bf16x8*)&WLo[bo];
            }
#pragma unroll
            for (int rt = 0; rt < 2; ++rt)
#pragma unroll
                for (int ct = 0; ct < 2; ++ct) {
                    xacc[rt][ct] = __builtin_amdgcn_mfma_f32_16x16x32_bf16(aH[rt], bH[ct],
                                                                           xacc[rt][ct], 0, 0, 0);
                    xacc[rt][ct] = __builtin_amdgcn_mfma_f32_16x16x32_bf16(aL[rt], bH[ct],
                                                                           xacc[rt][ct], 0, 0, 0);
                    xacc[rt][ct] = __builtin_amdgcn_mfma_f32_16x16x32_bf16(aH[rt], bL[ct],
                                                                           xacc[rt][ct], 0, 0, 0);
                }
        }
        const float bq0 = bq[0];
        float rowsum[2][4] = {{0.f, 0.f, 0.f, 0.f}, {0.f, 0.f, 0.f, 0.f}};
#pragma unroll
        for (int ct = 0; ct < 2; ++ct) {
            const int h = ch * 32 + ct * 16 + lm;
            const float c2 = c2base[b * 64 + h];
            const float wqh = Wq[h];
#pragma unroll
            for (int rt = 0; rt < 2; ++rt)
#pragma unroll
                for (int r = 0; r < 4; ++r)
                    rowsum[rt][r] += fmaxf(xacc[rt][ct][r] + c2, 0.f) * wqh;
        }
#pragma unroll
        for (int rt = 0; rt < 2; ++rt)
#pragma unroll
            for (int r = 0; r < 4; ++r) {
                float v = rowsum[rt][r];
                v += __shfl_xor(v, 1);
                v += __shfl_xor(v, 2);
                v += __shfl_xor(v, 4);
                v += __shfl_xor(v, 8);
                if (lm == 0) rpart[ch * 64 + rh * 32 + rt * 16 + q * 4 + r] = v;
            }
        __syncthreads();
        if (t < 64)
            out[(size_t)b * (Nc + 1) + n0 + t] = rpart[t] + rpart[64 + t] + bq0;
    }
}

// ---------------------------------------------------------------------------
// Fused rounds kernel: r0 -> r1 -> final -> tail. Fence-free barriers; X via
// MALL. Saves 3 kernel boundaries vs the split version.
// ---------------------------------------------------------------------------
__global__ __launch_bounds__(256, 2) void k_rounds3(
    const bf16* __restrict__ Afrag, bf16* __restrict__ Xf0, bf16* __restrict__ Xf1,
    const float* __restrict__ mu_1, const float* __restrict__ C3,
    const bf16* __restrict__ W2bf,
    const float* __restrict__ Wreg, const float* __restrict__ c2base,
    const float* __restrict__ Wq, const float* __restrict__ bq,
    const float* __restrict__ Wq1, const float* __restrict__ bq1,
    float* __restrict__ musum, float* __restrict__ out,
    unsigned* __restrict__ bar) {
    const int id = blockIdx.x, t = threadIdx.x;
    extern __shared__ char smem[];
    unsigned* cnt  = bar;
    unsigned* flag = bar + 32;   // 128B apart

    // stage WHi (bf16 W2) once; persists across both non-final rounds
    {
        bf16* WHi = (bf16*)smem;
#pragma unroll
        for (int i = 0; i < 2; ++i) {
            int g = i * 256 + t, row = g >> 3, c = g & 7;
            *(bf16x8*)&WHi[row * MS + c * 8] = *(const bf16x8*)&W2bf[row * 64 + c * 8];
        }
    }
    __syncthreads();

    // round 1: Xf0 from k_init (kernel boundary published) -> plain X loads
    round_body<false, false>(smem, id, Afrag, Xf0, mu_1, C3, Xf1,
                             nullptr, nullptr, nullptr, nullptr, nullptr, nullptr);
    sync_lite(cnt, flag, 1);
    // round 2: Xf1 written intra-kernel -> MALL loads
    round_body<false, true>(smem, id, Afrag, Xf1, mu_1, C3, Xf0,
                            nullptr, nullptr, nullptr, nullptr, nullptr, nullptr);
    sync_lite(cnt, flag, 2);
    // final: Xf0 written intra-kernel -> MALL loads
    round_body<true, true>(smem, id, Afrag, Xf0, mu_1, C3, nullptr,
                           Wreg, c2base, Wq, bq, musum, out);
    sync_lite(cnt, flag, 3);

    // ---- tail (mean row): blocks 0..31, musum via MALL ----
    if (id < 32) {
        const int b = id;
        float* mean_s = (float*)smem;
        float* mp     = (float*)(smem + 1024);
        if (t < 64)
            mean_s[t] = __hip_atomic_load(&musum[b * 64 + t],
                                          __ATOMIC_RELAXED, __HIP_MEMORY_SCOPE_AGENT)
                        * (1.f / Nc);
        __syncthreads();
        if (t < 64) {
            float a = bq1[t];
#pragma unroll
            for (int e = 0; e < 64; ++e) a = fmaf(mean_s[e], Wq1[t * 64 + e], a);
            mp[t] = fmaxf(a, 0.f);
        }
        __syncthreads();
        if (t < 64) {
            float h = c2base[b * 64 + t];
#pragma unroll
            for (int d = 0; d < 64; ++d) h = fmaf(mp[d], Wreg[t * 128 + d], h);
            float v = fmaxf(h, 0.f) * Wq[t];
#pragma unroll
            for (int off = 32; off; off >>= 1) v += __shfl_down(v, off);
            if (t == 0) out[(size_t)b * (Nc + 1) + Nc] = v + bq[0];
        }
    }
}

// ---------------------------------------------------------------------------
extern "C" void kernel_launch(void* const* d_in, const int* in_sizes, int n_in,
                              void* d_out, int out_size, void* d_ws, size_t ws_size,
                              hipStream_t stream) {
    const float* xv     = (const float*)d_in[0];
    const float* option = (const float*)d_in[1];
    const float* adj    = (const float*)d_in[2];
    const float* mu1w   = (const float*)d_in[3];
    const float* W2     = (const float*)d_in[4];
    const float* b2     = (const float*)d_in[5];
    const float* W3     = (const float*)d_in[6];
    const float* b3     = (const float*)d_in[7];
    const float* W4     = (const float*)d_in[8];
    const float* b4     = (const float*)d_in[9];
    const float* Wq1    = (const float*)d_in[10];
    const float* bq1    = (const float*)d_in[11];
    const float* Wq2    = (const float*)d_in[12];
    const float* bq2    = (const float*)d_in[13];
    const float* Wreg   = (const float*)d_in[14];
    const float* breg   = (const float*)d_in[15];
    const float* Wq     = (const float*)d_in[16];
    const float* bq     = (const float*)d_in[17];
    float* out = (float*)d_out;

    float* ws = (float*)d_ws;
    const size_t MU = (size_t)Bc * Nc * Dc;          // 2,097,152
    float* mu_1     = ws;
    float* C3       = ws + MU;                       // 65536
    float* c2base   = C3 + 65536;                    // 2048
    float* musum    = c2base + 2048;                 // 2048
    unsigned* bar   = (unsigned*)(musum + 2048);     // 64 uints (cnt@0, flag@32)
    bf16*  Afrag    = (bf16*)(bar + 64);             // 1M bf16
    bf16*  W2bf     = Afrag + (size_t)Nc * Nc;       // 4096 bf16
    bf16*  Xf0      = W2bf + 4096;                   // B*64K bf16
    bf16*  Xf1      = Xf0 + MU;

    k_init<<<1537, 256, 0, stream>>>(adj, W4, b4, W3, b3, b2, W2, option, Wq2, bq2,
                                     Wreg, breg, xv, mu1w,
                                     Afrag, C3, W2bf, c2base, musum, mu_1, Xf0, bar);
    k_rounds3<<<NBLK, 256, LDS_RND, stream>>>(
        Afrag, Xf0, Xf1, mu_1, C3, W2bf,
        Wreg, c2base, Wq, bq, Wq1, bq1, musum, out, bar);
}